// Round 1
// baseline (354.557 us; speedup 1.0000x reference)
//
#include <hip/hip_runtime.h>
#include <math.h>

#define NELEM 10
#define DCH 32
#define NB 8
#define HID 64

__device__ __forceinline__ float wave_reduce(float v) {
    #pragma unroll
    for (int off = 32; off > 0; off >>= 1) v += __shfl_down(v, off, 64);
    return v;
}

// K0: per-species table U[z][k] = sum_c W2[k, c] * W_out[c] * W_z[z, c]  (l=0 block of W2)
//     s[k] = silu(b1[k]);  q[z] = sum_k s[k] * U[z][k]
__global__ void k_pre(const float* __restrict__ Wz, const float* __restrict__ b1,
                      const float* __restrict__ W2, const float* __restrict__ Wout,
                      float* __restrict__ U, float* __restrict__ s, float* __restrict__ q) {
    int t = threadIdx.x;
    if (t < HID) {
        float x = b1[t];
        s[t] = x / (1.f + __expf(-x));
    }
    for (int i = t; i < NELEM * HID; i += blockDim.x) {
        int z = i / HID, k = i - z * HID;
        float acc = 0.f;
        for (int c = 0; c < DCH; ++c)
            acc += W2[k * (4 * DCH) + c] * Wout[c] * Wz[z * DCH + c];
        U[i] = acc;
    }
    __syncthreads();
    if (t < NELEM) {
        float acc = 0.f;
        for (int k = 0; k < HID; ++k) acc += s[k] * U[t * HID + k];
        q[t] = acc;
    }
}

// K1: streaming edge pass — distance test, out-degree histogram, close-edge compaction
__global__ void k_edges(const float* __restrict__ pos, const float* __restrict__ shifts,
                        const int* __restrict__ ei, int E,
                        int* __restrict__ deg, int* __restrict__ cnt, int* __restrict__ list) {
    int gid = blockIdx.x * blockDim.x + threadIdx.x;
    int stride = gridDim.x * blockDim.x;
    for (int e = gid; e < E; e += stride) {
        int snd = ei[e];
        int rcv = ei[E + e];
        float dx = (pos[3 * rcv + 0] - pos[3 * snd + 0]) * 10.f + shifts[3 * e + 0];
        float dy = (pos[3 * rcv + 1] - pos[3 * snd + 1]) * 10.f + shifts[3 * e + 1];
        float dz = (pos[3 * rcv + 2] - pos[3 * snd + 2]) * 10.f + shifts[3 * e + 2];
        float d2 = dx * dx + dy * dy + dz * dz;
        atomicAdd(&deg[snd], 1);
        if (d2 < 25.f) {
            int idx = atomicAdd(cnt, 1);
            list[idx] = e;
        }
    }
}

// K2: dense compute over compacted close edges
__global__ __launch_bounds__(256) void k_close(
        const float* __restrict__ pos, const float* __restrict__ na,
        const float* __restrict__ shifts, const int* __restrict__ ei, int E,
        const float* __restrict__ W1, const float* __restrict__ b1,
        const float* __restrict__ Ug, const float* __restrict__ sg,
        const int* __restrict__ cnt, const int* __restrict__ list,
        float* __restrict__ out_sum) {
    __shared__ float W1s[NB * HID];
    __shared__ float b1s[HID];
    __shared__ float Us[NELEM * HID];
    __shared__ float ss[HID];
    int t = threadIdx.x;
    for (int i = t; i < NB * HID; i += blockDim.x) W1s[i] = W1[i];
    for (int i = t; i < NELEM * HID; i += blockDim.x) Us[i] = Ug[i];
    if (t < HID) { b1s[t] = b1[t]; ss[t] = sg[t]; }
    __syncthreads();

    int n = *cnt;
    int gid = blockIdx.x * blockDim.x + t;
    int stride = gridDim.x * blockDim.x;
    float acc = 0.f;
    const float PI = 3.14159265358979f;

    for (int i = gid; i < n; i += stride) {
        int e = list[i];
        int snd = ei[e], rcv = ei[E + e];
        float dx = (pos[3 * rcv + 0] - pos[3 * snd + 0]) * 10.f + shifts[3 * e + 0];
        float dy = (pos[3 * rcv + 1] - pos[3 * snd + 1]) * 10.f + shifts[3 * e + 1];
        float dz = (pos[3 * rcv + 2] - pos[3 * snd + 2]) * 10.f + shifts[3 * e + 2];
        float d2 = dx * dx + dy * dy + dz * dz;
        float r = sqrtf(d2 + 1e-12f);

        // polynomial cutoff (p=6): 1 - 28u^6 + 48u^7 - 21u^8, zero for u >= 1
        float u = r * 0.2f;
        float u2 = u * u, u4 = u2 * u2, u6 = u4 * u2;
        float fc = 1.f - 28.f * u6 + 48.f * u6 * u - 21.f * u6 * u2;
        if (u >= 1.f) fc = 0.f;

        // Bessel basis via Chebyshev recurrence: sin(n*th), th = pi*r/5
        float th = PI * r * 0.2f;
        float sn, cs;
        __sincosf(th, &sn, &cs);
        float pref = 0.632455532f / r * fc;   // sqrt(2/5)/r * fc
        float bas[NB];
        float sp = 0.f, sc = sn;
        float twoc = 2.f * cs;
        #pragma unroll
        for (int nb = 0; nb < NB; ++nb) {
            bas[nb] = pref * sc;
            float nx = twoc * sc - sp;
            sp = sc; sc = nx;
        }

        float naz[NELEM];
        #pragma unroll
        for (int z = 0; z < NELEM; ++z) naz[z] = na[snd * NELEM + z];

        float local = 0.f;
        for (int k = 0; k < HID; ++k) {
            float a = b1s[k];
            #pragma unroll
            for (int nb = 0; nb < NB; ++nb) a += bas[nb] * W1s[nb * HID + k];
            float h = a / (1.f + __expf(-a));   // silu
            float us = 0.f;
            #pragma unroll
            for (int z = 0; z < NELEM; ++z) us += naz[z] * Us[z * HID + k];
            local += (h - ss[k]) * us;
        }
        acc += local;
    }

    acc = wave_reduce(acc);
    if ((t & 63) == 0) atomicAdd(out_sum, acc);
}

// K3: m[z] = sum_n deg[n] * node_attrs[n, z]
__global__ void k_nodes(const float* __restrict__ na, const int* __restrict__ deg,
                        int N, float* __restrict__ m) {
    int gid = blockIdx.x * blockDim.x + threadIdx.x;
    int stride = gridDim.x * blockDim.x;
    float loc[NELEM];
    #pragma unroll
    for (int z = 0; z < NELEM; ++z) loc[z] = 0.f;
    for (int i = gid; i < N; i += stride) {
        float dg = (float)deg[i];
        if (dg != 0.f) {
            #pragma unroll
            for (int z = 0; z < NELEM; ++z) loc[z] += dg * na[i * NELEM + z];
        }
    }
    #pragma unroll
    for (int z = 0; z < NELEM; ++z) {
        float v = wave_reduce(loc[z]);
        if ((threadIdx.x & 63) == 0) atomicAdd(&m[z], v);
    }
}

// K4: energy = (close_sum + sum_z m[z]*q[z]) * eV->kJ/mol
__global__ void k_final(const float* __restrict__ csum, const float* __restrict__ m,
                        const float* __restrict__ q, float* __restrict__ out) {
    float t2 = 0.f;
    #pragma unroll
    for (int z = 0; z < NELEM; ++z) t2 += m[z] * q[z];
    out[0] = (csum[0] + t2) * 96.4853f;
}

extern "C" void kernel_launch(void* const* d_in, const int* in_sizes, int n_in,
                              void* d_out, int out_size, void* d_ws, size_t ws_size,
                              hipStream_t stream) {
    const float* pos    = (const float*)d_in[0];
    const float* na     = (const float*)d_in[1];
    const float* shifts = (const float*)d_in[2];
    const float* Wz     = (const float*)d_in[3];
    const float* W1     = (const float*)d_in[4];
    const float* b1     = (const float*)d_in[5];
    const float* W2     = (const float*)d_in[6];
    const float* Wout   = (const float*)d_in[7];
    const int*   ei     = (const int*)d_in[8];
    int N = in_sizes[0] / 3;
    int E = in_sizes[8] / 2;

    char* ws = (char*)d_ws;
    float* close_sum = (float*)(ws + 0);       // 1 float
    float* m         = (float*)(ws + 16);      // 10 floats
    float* q         = (float*)(ws + 64);      // 10 floats
    float* s         = (float*)(ws + 128);     // 64 floats (ends at 384)
    float* U         = (float*)(ws + 384);     // 640 floats (ends at 2944)
    int*   cnt       = (int*)(ws + 2944);      // 1 int
    int*   deg       = (int*)(ws + 3072);      // N ints
    size_t deg_bytes = (((size_t)N * 4) + 255) / 256 * 256;
    int*   list      = (int*)(ws + 3072 + deg_bytes);  // up to E ints

    // zero accumulators + deg each call (ws is not re-poisoned between replays)
    hipMemsetAsync(d_ws, 0, 3072 + (size_t)N * 4, stream);

    k_pre<<<1, 256, 0, stream>>>(Wz, b1, W2, Wout, U, s, q);

    int blocks1 = (E + 255) / 256;
    k_edges<<<blocks1, 256, 0, stream>>>(pos, shifts, ei, E, deg, cnt, list);

    k_close<<<512, 256, 0, stream>>>(pos, na, shifts, ei, E, W1, b1, U, s,
                                     cnt, list, close_sum);

    int blocks3 = (N + 255) / 256;
    k_nodes<<<blocks3, 256, 0, stream>>>(na, deg, N, m);

    k_final<<<1, 1, 0, stream>>>(close_sum, m, q, (float*)d_out);
}

// Round 2
// 245.261 us; speedup vs baseline: 1.4456x; 1.4456x over previous
//
#include <hip/hip_runtime.h>
#include <math.h>

#define NELEM 10
#define DCH 32
#define NB 8
#define HID 64
#define W2COLS (4 * DCH)
#define EKJ 96.4853f

__device__ __forceinline__ float wave_reduce(float v) {
    #pragma unroll
    for (int off = 32; off > 0; off >>= 1) v += __shfl_down(v, off, 64);
    return v;
}
__device__ __forceinline__ float silu_f(float x) { return x / (1.f + __expf(-x)); }

// K0: per-node prep. pos4[n] = positions*10 (Angstrom, padded float4);
// w[n] = sum_z na[n,z] * q[z], where q[z] = sum_k silu(b1)[k] * U[z][k],
// U[z][k] = sum_c W2[k, c] * Wout[c] * Wz[z, c]  (l=0 block of W2).
// Block 0 additionally publishes s[], U[] for k_close and zeroes accumulators.
__global__ __launch_bounds__(256) void k_prep(
        const float* __restrict__ pos, const float* __restrict__ na,
        const float* __restrict__ Wz, const float* __restrict__ b1,
        const float* __restrict__ W2, const float* __restrict__ Wout,
        int N, float4* __restrict__ pos4, float* __restrict__ wv,
        float* __restrict__ Ug, float* __restrict__ sg, float* __restrict__ accs) {
    __shared__ float ssh[HID], gsh[DCH], qsh[NELEM];
    int t = threadIdx.x;
    if (t < HID) ssh[t] = silu_f(b1[t]);
    __syncthreads();
    if (t < DCH) {  // g[c] = sum_k s[k] * W2[k, c]
        float g = 0.f;
        for (int k = 0; k < HID; ++k) g += ssh[k] * W2[k * W2COLS + t];
        gsh[t] = g;
    }
    __syncthreads();
    if (t < NELEM) {  // q[z] = sum_c g[c] * Wout[c] * Wz[z, c]
        float a = 0.f;
        for (int c = 0; c < DCH; ++c) a += gsh[c] * Wout[c] * Wz[t * DCH + c];
        qsh[t] = a;
    }
    __syncthreads();
    int n = blockIdx.x * 256 + t;
    if (n < N) {
        float x = pos[3 * n] * 10.f, y = pos[3 * n + 1] * 10.f, z = pos[3 * n + 2] * 10.f;
        pos4[n] = make_float4(x, y, z, 0.f);
        float a = 0.f;
        #pragma unroll
        for (int zz = 0; zz < NELEM; ++zz) a += na[n * NELEM + zz] * qsh[zz];
        wv[n] = a;
    }
    if (blockIdx.x == 0) {
        if (t < HID) sg[t] = ssh[t];
        for (int i = t; i < NELEM * HID; i += 256) {
            int z = i / HID, k = i - z * HID;
            float a = 0.f;
            for (int c = 0; c < DCH; ++c) a += W2[k * W2COLS + c] * Wout[c] * Wz[z * DCH + c];
            Ug[i] = a;
        }
        if (t == 0) {
            accs[0] = 0.f;           // close_sum
            accs[1] = 0.f;           // sum_w
            ((int*)accs)[2] = 0;     // cnt
            ((int*)accs)[3] = 0;     // done
        }
    }
}

// K1: streaming edge pass. Accumulate w[snd] (all-edges term), ballot-compact
// close edges (d < 5 Angstrom). No per-edge global atomics on data arrays.
__global__ __launch_bounds__(256) void k_edges(
        const float4* __restrict__ pos4, const float* __restrict__ wv,
        const float* __restrict__ shifts, const int* __restrict__ ei, int E,
        float* __restrict__ sum_w, int* __restrict__ cnt, int* __restrict__ list) {
    __shared__ float red[4];
    int t = threadIdx.x;
    int lane = t & 63;
    float acc = 0.f;
    for (int e = blockIdx.x * 256 + t; e < E; e += gridDim.x * 256) {
        int snd = ei[e], rcv = ei[E + e];
        float4 ps = pos4[snd];
        float4 pr = pos4[rcv];
        float dx = pr.x - ps.x + shifts[3 * e + 0];
        float dy = pr.y - ps.y + shifts[3 * e + 1];
        float dz = pr.z - ps.z + shifts[3 * e + 2];
        float d2 = dx * dx + dy * dy + dz * dz;
        acc += wv[snd];
        bool close = d2 < 25.f;
        unsigned long long mask = __ballot(close);
        if (mask) {
            int leader = __ffsll(mask) - 1;
            int base;
            if (lane == leader) base = atomicAdd(cnt, __popcll(mask));
            base = __shfl(base, leader, 64);
            if (close) {
                int off = __popcll(mask & ((1ULL << lane) - 1ULL));
                list[base + off] = e;
            }
        }
    }
    acc = wave_reduce(acc);
    if (lane == 0) red[t >> 6] = acc;
    __syncthreads();
    if (t == 0) atomicAdd(sum_w, red[0] + red[1] + red[2] + red[3]);
}

// K2: dense compute over compacted close edges + final combine (done-ticket).
__global__ __launch_bounds__(256) void k_close(
        const float4* __restrict__ pos4, const float* __restrict__ na,
        const float* __restrict__ shifts, const int* __restrict__ ei, int E,
        const float* __restrict__ W1, const float* __restrict__ b1,
        const float* __restrict__ Ug, const float* __restrict__ sg,
        const int* __restrict__ cnt, const int* __restrict__ list,
        float* __restrict__ close_sum, float* __restrict__ sum_w,
        int* __restrict__ done, float* __restrict__ out) {
    __shared__ float W1s[NB * HID];
    __shared__ float Us[NELEM * HID];
    __shared__ float b1s[HID], ss[HID];
    __shared__ float red[4];
    int t = threadIdx.x;
    for (int i = t; i < NB * HID; i += 256) W1s[i] = W1[i];
    for (int i = t; i < NELEM * HID; i += 256) Us[i] = Ug[i];
    if (t < HID) { b1s[t] = b1[t]; ss[t] = sg[t]; }
    __syncthreads();

    int n = *cnt;
    float acc = 0.f;
    const float PI = 3.14159265358979f;
    for (int i = blockIdx.x * 256 + t; i < n; i += gridDim.x * 256) {
        int e = list[i];
        int snd = ei[e], rcv = ei[E + e];
        float4 ps = pos4[snd], pr = pos4[rcv];
        float dx = pr.x - ps.x + shifts[3 * e + 0];
        float dy = pr.y - ps.y + shifts[3 * e + 1];
        float dz = pr.z - ps.z + shifts[3 * e + 2];
        float d2 = dx * dx + dy * dy + dz * dz;
        float r = sqrtf(d2 + 1e-12f);

        // polynomial cutoff (p=6): 1 - 28u^6 + 48u^7 - 21u^8, zero for u >= 1
        float u = r * 0.2f;
        float u2 = u * u, u4 = u2 * u2, u6 = u4 * u2;
        float fc = 1.f - 28.f * u6 + 48.f * u6 * u - 21.f * u6 * u2;
        if (u >= 1.f) fc = 0.f;

        // Bessel basis via Chebyshev recurrence on sin(n*th), th = pi*r/5
        float th = PI * r * 0.2f;
        float sn, cs;
        __sincosf(th, &sn, &cs);
        float pref = 0.632455532f / r * fc;  // sqrt(2/5)/r * fc
        float bas[NB];
        float sp = 0.f, sc = sn;
        float twoc = 2.f * cs;
        #pragma unroll
        for (int nb = 0; nb < NB; ++nb) {
            bas[nb] = pref * sc;
            float nx = twoc * sc - sp;
            sp = sc; sc = nx;
        }

        float naz[NELEM];
        #pragma unroll
        for (int z = 0; z < NELEM; ++z) naz[z] = na[snd * NELEM + z];

        float local = 0.f;
        for (int k = 0; k < HID; ++k) {
            float a = b1s[k];
            #pragma unroll
            for (int nb = 0; nb < NB; ++nb) a += bas[nb] * W1s[nb * HID + k];
            float h = a / (1.f + __expf(-a));  // silu
            float us = 0.f;
            #pragma unroll
            for (int z = 0; z < NELEM; ++z) us += naz[z] * Us[z * HID + k];
            local += (h - ss[k]) * us;
        }
        acc += local;
    }

    acc = wave_reduce(acc);
    if ((t & 63) == 0) red[t >> 6] = acc;
    __syncthreads();
    if (t == 0) {
        atomicAdd(close_sum, red[0] + red[1] + red[2] + red[3]);
        __threadfence();
        int tk = atomicAdd(done, 1);
        if (tk == (int)gridDim.x - 1) {
            float cs = atomicAdd(close_sum, 0.f);  // coherent reads
            float sw = atomicAdd(sum_w, 0.f);
            out[0] = (cs + sw) * EKJ;
        }
    }
}

extern "C" void kernel_launch(void* const* d_in, const int* in_sizes, int n_in,
                              void* d_out, int out_size, void* d_ws, size_t ws_size,
                              hipStream_t stream) {
    const float* pos    = (const float*)d_in[0];
    const float* na     = (const float*)d_in[1];
    const float* shifts = (const float*)d_in[2];
    const float* Wz     = (const float*)d_in[3];
    const float* W1     = (const float*)d_in[4];
    const float* b1     = (const float*)d_in[5];
    const float* W2     = (const float*)d_in[6];
    const float* Wout   = (const float*)d_in[7];
    const int*   ei     = (const int*)d_in[8];
    int N = in_sizes[0] / 3;
    int E = in_sizes[8] / 2;

    char* ws = (char*)d_ws;
    float* accs      = (float*)(ws + 0);        // [0] close_sum, [1] sum_w, [2] cnt(int), [3] done(int)
    float* close_sum = (float*)(ws + 0);
    float* sum_w     = (float*)(ws + 4);
    int*   cnt       = (int*)(ws + 8);
    int*   done      = (int*)(ws + 12);
    float* sg        = (float*)(ws + 64);       // 64 floats
    float* Ug        = (float*)(ws + 384);      // 640 floats, ends 2944
    float4* pos4     = (float4*)(ws + 3072);    // N*16 B, ends 3072 + 800000
    float* wv        = (float*)(ws + 3072 + (size_t)N * 16);
    int*   list      = (int*)(ws + 3072 + (size_t)N * 16 + (size_t)N * 4 + 256);

    int blocksP = (N + 255) / 256;
    k_prep<<<blocksP, 256, 0, stream>>>(pos, na, Wz, b1, W2, Wout, N, pos4, wv, Ug, sg, accs);

    k_edges<<<2048, 256, 0, stream>>>(pos4, wv, shifts, ei, E, sum_w, cnt, list);

    k_close<<<256, 256, 0, stream>>>(pos4, na, shifts, ei, E, W1, b1, Ug, sg,
                                     cnt, list, close_sum, sum_w, done, (float*)d_out);
}

// Round 3
// 115.803 us; speedup vs baseline: 3.0617x; 2.1179x over previous
//
#include <hip/hip_runtime.h>
#include <math.h>

#define NELEM 10
#define DCH 32
#define NB 8
#define HID 64
#define W2COLS (4 * DCH)
#define EKJ 96.4853f
#define NPART 2048
#define USTR (HID + 1)   // padded LDS row stride for U (break same-bank rows)

__device__ __forceinline__ float wave_reduce(float v) {
    #pragma unroll
    for (int off = 32; off > 0; off >>= 1) v += __shfl_down(v, off, 64);
    return v;
}
__device__ __forceinline__ float silu_f(float x) { return x / (1.f + __expf(-x)); }

// K0: per-node prep.
//   pos4[n] = (x,y,z in Angstrom, w[n])   where w[n] = sum_z na[n,z]*q[z]
//   spec[n] = argmax_z na[n,z]            (na is exactly one-hot)
//   Ug[z][k] = sum_c W2[k,c]*Wout[c]*Wz[z,c]   (l=0 block of W2), block 0 only
//   q[z] = sum_k silu(b1)[k] * Ug[z][k]
__global__ __launch_bounds__(256) void k_prep(
        const float* __restrict__ pos, const float* __restrict__ na,
        const float* __restrict__ Wz, const float* __restrict__ b1,
        const float* __restrict__ W2, const float* __restrict__ Wout,
        int N, float4* __restrict__ pos4, int* __restrict__ spec,
        float* __restrict__ Ug) {
    __shared__ float ssh[HID], gsh[DCH], qsh[NELEM];
    int t = threadIdx.x;
    if (t < HID) ssh[t] = silu_f(b1[t]);
    __syncthreads();
    if (t < DCH) {  // g[c] = sum_k s[k] * W2[k,c]
        float g = 0.f;
        for (int k = 0; k < HID; ++k) g += ssh[k] * W2[k * W2COLS + t];
        gsh[t] = g;
    }
    __syncthreads();
    if (t < NELEM) {  // q[z] = sum_c g[c]*Wout[c]*Wz[z,c]
        float a = 0.f;
        for (int c = 0; c < DCH; ++c) a += gsh[c] * Wout[c] * Wz[t * DCH + c];
        qsh[t] = a;
    }
    __syncthreads();
    int n = blockIdx.x * 256 + t;
    if (n < N) {
        float x = pos[3 * n] * 10.f, y = pos[3 * n + 1] * 10.f, z = pos[3 * n + 2] * 10.f;
        float a = 0.f; int sp = 0; float best = -1e30f;
        #pragma unroll
        for (int zz = 0; zz < NELEM; ++zz) {
            float v = na[n * NELEM + zz];
            a += v * qsh[zz];
            if (v > best) { best = v; sp = zz; }
        }
        pos4[n] = make_float4(x, y, z, a);
        spec[n] = sp;
    }
    if (blockIdx.x == 0) {
        for (int i = t; i < NELEM * HID; i += 256) {
            int z = i / HID, k = i - z * HID;
            float a = 0.f;
            for (int c = 0; c < DCH; ++c) a += W2[k * W2COLS + c] * Wout[c] * Wz[z * DCH + c];
            Ug[i] = a;
        }
    }
}

// K1: fused streaming edge pass. No atomics, no compaction, no inter-block comm.
// Light path per edge: gather pos4[snd],pos4[rcv], accumulate w. Close edges
// (~2%) run the radial-MLP delta term under the exec mask with the one-hot
// species row of U.
__global__ __launch_bounds__(256) void k_fused(
        const float4* __restrict__ pos4, const int* __restrict__ spec,
        const float* __restrict__ shifts, const int* __restrict__ ei, int E,
        const float* __restrict__ W1, const float* __restrict__ b1,
        const float* __restrict__ Ug,
        float* __restrict__ part_c, float* __restrict__ part_w) {
    __shared__ float W1s[NB * HID];
    __shared__ float Us[NELEM * USTR];
    __shared__ float b1s[HID], ss[HID];
    __shared__ float red[8];
    int t = threadIdx.x;
    for (int i = t; i < NB * HID; i += 256) W1s[i] = W1[i];
    for (int i = t; i < NELEM * HID; i += 256) {
        int z = i / HID, k = i - z * HID;
        Us[z * USTR + k] = Ug[i];
    }
    if (t < HID) { float b = b1[t]; b1s[t] = b; ss[t] = silu_f(b); }
    __syncthreads();

    float accw = 0.f, accc = 0.f;
    const float PI = 3.14159265358979f;
    for (int e = blockIdx.x * 256 + t; e < E; e += gridDim.x * 256) {
        int snd = ei[e], rcv = ei[E + e];
        float4 ps = pos4[snd], pr = pos4[rcv];
        float dx = pr.x - ps.x + shifts[3 * e + 0];
        float dy = pr.y - ps.y + shifts[3 * e + 1];
        float dz = pr.z - ps.z + shifts[3 * e + 2];
        float d2 = dx * dx + dy * dy + dz * dz;
        accw += ps.w;
        if (d2 < 25.f) {
            float r = sqrtf(d2 + 1e-12f);
            // polynomial cutoff p=6: 1 - 28u^6 + 48u^7 - 21u^8 (u<1 here)
            float u = r * 0.2f;
            float u2 = u * u, u4 = u2 * u2, u6 = u4 * u2;
            float fc = 1.f - 28.f * u6 + 48.f * u6 * u - 21.f * u6 * u2;
            // Bessel via Chebyshev recurrence on sin(n*th), th = pi*r/5
            float th = PI * r * 0.2f;
            float sn, cs;
            __sincosf(th, &sn, &cs);
            float pref = 0.632455532f / r * fc;  // sqrt(2/5)/r * fc
            float bas[NB];
            float sp_ = 0.f, sc = sn, twoc = 2.f * cs;
            #pragma unroll
            for (int nb = 0; nb < NB; ++nb) {
                bas[nb] = pref * sc;
                float nx = twoc * sc - sp_;
                sp_ = sc; sc = nx;
            }
            int sz = spec[snd];
            const float* Urow = &Us[sz * USTR];
            float local = 0.f;
            for (int k = 0; k < HID; ++k) {
                float a = b1s[k];
                #pragma unroll
                for (int nb = 0; nb < NB; ++nb) a += bas[nb] * W1s[nb * HID + k];
                float h = a / (1.f + __expf(-a));  // silu
                local += (h - ss[k]) * Urow[k];
            }
            accc += local;
        }
    }

    accw = wave_reduce(accw);
    accc = wave_reduce(accc);
    int wid = t >> 6;
    if ((t & 63) == 0) { red[wid] = accw; red[4 + wid] = accc; }
    __syncthreads();
    if (t == 0) {
        part_w[blockIdx.x] = red[0] + red[1] + red[2] + red[3];
        part_c[blockIdx.x] = red[4] + red[5] + red[6] + red[7];
    }
}

// K2: reduce 2*NPART partials, write scalar output.
__global__ __launch_bounds__(256) void k_final(
        const float* __restrict__ part_c, const float* __restrict__ part_w,
        float* __restrict__ out) {
    __shared__ float red[4];
    int t = threadIdx.x;
    float s = 0.f;
    for (int i = t; i < 2 * NPART; i += 256)
        s += (i < NPART) ? part_c[i] : part_w[i - NPART];
    s = wave_reduce(s);
    if ((t & 63) == 0) red[t >> 6] = s;
    __syncthreads();
    if (t == 0) out[0] = (red[0] + red[1] + red[2] + red[3]) * EKJ;
}

extern "C" void kernel_launch(void* const* d_in, const int* in_sizes, int n_in,
                              void* d_out, int out_size, void* d_ws, size_t ws_size,
                              hipStream_t stream) {
    const float* pos    = (const float*)d_in[0];
    const float* na     = (const float*)d_in[1];
    const float* shifts = (const float*)d_in[2];
    const float* Wz     = (const float*)d_in[3];
    const float* W1     = (const float*)d_in[4];
    const float* b1     = (const float*)d_in[5];
    const float* W2     = (const float*)d_in[6];
    const float* Wout   = (const float*)d_in[7];
    const int*   ei     = (const int*)d_in[8];
    int N = in_sizes[0] / 3;
    int E = in_sizes[8] / 2;

    char* ws = (char*)d_ws;
    float*  Ug     = (float*)(ws + 0);                       // 640 floats
    float4* pos4   = (float4*)(ws + 4096);                   // N*16 B
    int*    spec   = (int*)(ws + 4096 + (size_t)N * 16);     // N*4 B
    float*  part_c = (float*)(ws + 4096 + (size_t)N * 20);   // NPART floats
    float*  part_w = part_c + NPART;                          // NPART floats

    int blocksP = (N + 255) / 256;
    k_prep<<<blocksP, 256, 0, stream>>>(pos, na, Wz, b1, W2, Wout, N, pos4, spec, Ug);

    k_fused<<<NPART, 256, 0, stream>>>(pos4, spec, shifts, ei, E, W1, b1, Ug,
                                       part_c, part_w);

    k_final<<<1, 256, 0, stream>>>(part_c, part_w, (float*)d_out);
}

// Round 4
// 40.975 us; speedup vs baseline: 8.6530x; 2.8262x over previous
//
#include <hip/hip_runtime.h>
#include <math.h>

#define NELEM 10
#define DCH 32
#define NB 8
#define HID 64
#define W2COLS (4 * DCH)
#define EKJ 96.4853f
#define NPART 1024
#define USTR (HID + 1)   // padded LDS row stride for U
#define QCAP 1024

__device__ __forceinline__ float wave_reduce(float v) {
    #pragma unroll
    for (int off = 32; off > 0; off >>= 1) v += __shfl_down(v, off, 64);
    return v;
}
__device__ __forceinline__ float silu_f(float x) { return x / (1.f + __expf(-x)); }

// Close-edge contribution: (silu(basis@W1 + b1) - silu(b1)) . U[spec]
__device__ __forceinline__ float edge_term(float r, int sz,
        const float* __restrict__ W1s, const float* __restrict__ b1s,
        const float* __restrict__ ss, const float* __restrict__ Us) {
    const float PI = 3.14159265358979f;
    // polynomial cutoff p=6 (r < 5 guaranteed): 1 - 28u^6 + 48u^7 - 21u^8
    float u = r * 0.2f;
    float u2 = u * u, u4 = u2 * u2, u6 = u4 * u2;
    float fc = 1.f - 28.f * u6 + 48.f * u6 * u - 21.f * u6 * u2;
    // Bessel basis via Chebyshev recurrence on sin(n*th), th = pi*r/5
    float th = PI * r * 0.2f;
    float sn, cs;
    __sincosf(th, &sn, &cs);
    float pref = 0.632455532f / r * fc;  // sqrt(2/5)/r * fc
    float bas[NB];
    float sp_ = 0.f, sc = sn, twoc = 2.f * cs;
    #pragma unroll
    for (int nb = 0; nb < NB; ++nb) {
        bas[nb] = pref * sc;
        float nx = twoc * sc - sp_;
        sp_ = sc; sc = nx;
    }
    const float* Urow = &Us[sz * USTR];
    float local = 0.f;
    for (int k = 0; k < HID; ++k) {
        float a = b1s[k];
        #pragma unroll
        for (int nb = 0; nb < NB; ++nb) a += bas[nb] * W1s[nb * HID + k];
        float h = a / (1.f + __expf(-a));  // silu
        local += (h - ss[k]) * Urow[k];
    }
    return local;
}

// K0: per-node prep.
//   pos4[n] = (x,y,z Angstrom, w[n]) with w[n] = sum_z na[n,z]*q[z]
//   spec[n] = argmax_z na[n,z]  (na is exactly one-hot)
//   Ug[z][k] = sum_c W2[k,c]*Wout[c]*Wz[z,c]  (l=0 block), block 0 only
__global__ __launch_bounds__(256) void k_prep(
        const float* __restrict__ pos, const float* __restrict__ na,
        const float* __restrict__ Wz, const float* __restrict__ b1,
        const float* __restrict__ W2, const float* __restrict__ Wout,
        int N, float4* __restrict__ pos4, int* __restrict__ spec,
        float* __restrict__ Ug) {
    __shared__ float ssh[HID], gsh[DCH], qsh[NELEM];
    int t = threadIdx.x;
    if (t < HID) ssh[t] = silu_f(b1[t]);
    __syncthreads();
    if (t < DCH) {  // g[c] = sum_k s[k] * W2[k,c]
        float g = 0.f;
        for (int k = 0; k < HID; ++k) g += ssh[k] * W2[k * W2COLS + t];
        gsh[t] = g;
    }
    __syncthreads();
    if (t < NELEM) {  // q[z] = sum_c g[c]*Wout[c]*Wz[z,c]
        float a = 0.f;
        for (int c = 0; c < DCH; ++c) a += gsh[c] * Wout[c] * Wz[t * DCH + c];
        qsh[t] = a;
    }
    __syncthreads();
    int n = blockIdx.x * 256 + t;
    if (n < N) {
        float x = pos[3 * n] * 10.f, y = pos[3 * n + 1] * 10.f, z = pos[3 * n + 2] * 10.f;
        float a = 0.f; int sp = 0; float best = -1e30f;
        #pragma unroll
        for (int zz = 0; zz < NELEM; ++zz) {
            float v = na[n * NELEM + zz];
            a += v * qsh[zz];
            if (v > best) { best = v; sp = zz; }
        }
        pos4[n] = make_float4(x, y, z, a);
        spec[n] = sp;
    }
    if (blockIdx.x == 0) {
        for (int i = t; i < NELEM * HID; i += 256) {
            int z = i / HID, k = i - z * HID;
            float a = 0.f;
            for (int c = 0; c < DCH; ++c) a += W2[k * W2COLS + c] * Wout[c] * Wz[z * DCH + c];
            Ug[i] = a;
        }
    }
}

// K1: fused streaming pass with block-local LDS compaction of close edges.
// Light path classifies; close edges enqueue (r, spec) to LDS; one dense
// flush at the end runs the MLP with full lane occupancy.
__global__ __launch_bounds__(256) void k_fused(
        const float4* __restrict__ pos4, const int* __restrict__ spec,
        const float* __restrict__ shifts, const int* __restrict__ ei, int E,
        const float* __restrict__ W1, const float* __restrict__ b1,
        const float* __restrict__ Ug,
        float* __restrict__ part_c, float* __restrict__ part_w) {
    __shared__ float W1s[NB * HID];
    __shared__ float Us[NELEM * USTR];
    __shared__ float b1s[HID], ss[HID];
    __shared__ float qr[QCAP];
    __shared__ int qs[QCAP];
    __shared__ int qn;
    __shared__ float red[8];
    int t = threadIdx.x;
    for (int i = t; i < NB * HID; i += 256) W1s[i] = W1[i];
    for (int i = t; i < NELEM * HID; i += 256) {
        int z = i / HID, k = i - z * HID;
        Us[z * USTR + k] = Ug[i];
    }
    if (t < HID) { float b = b1[t]; b1s[t] = b; ss[t] = silu_f(b); }
    if (t == 0) qn = 0;
    __syncthreads();

    float accw = 0.f, accc = 0.f;
    for (int base = blockIdx.x * 256; base < E; base += gridDim.x * 256) {
        int e = base + t;
        if (e < E) {
            int snd = ei[e], rcv = ei[E + e];
            float4 ps = pos4[snd], pr = pos4[rcv];
            float dx = pr.x - ps.x + shifts[3 * e + 0];
            float dy = pr.y - ps.y + shifts[3 * e + 1];
            float dz = pr.z - ps.z + shifts[3 * e + 2];
            float d2 = dx * dx + dy * dy + dz * dz;
            accw += ps.w;
            if (d2 < 25.f) {
                float r = sqrtf(d2 + 1e-12f);
                int sz = spec[snd];
                int idx = atomicAdd(&qn, 1);
                if (idx < QCAP) { qr[idx] = r; qs[idx] = sz; }
                else accc += edge_term(r, sz, W1s, b1s, ss, Us);  // overflow fallback
            }
        }
    }
    __syncthreads();
    int n = qn < QCAP ? qn : QCAP;
    for (int i = t; i < n; i += 256)
        accc += edge_term(qr[i], qs[i], W1s, b1s, ss, Us);

    accw = wave_reduce(accw);
    accc = wave_reduce(accc);
    int wid = t >> 6;
    if ((t & 63) == 0) { red[wid] = accw; red[4 + wid] = accc; }
    __syncthreads();
    if (t == 0) {
        part_w[blockIdx.x] = red[0] + red[1] + red[2] + red[3];
        part_c[blockIdx.x] = red[4] + red[5] + red[6] + red[7];
    }
}

// K2: reduce partials, write scalar output.
__global__ __launch_bounds__(256) void k_final(
        const float* __restrict__ part_c, const float* __restrict__ part_w,
        float* __restrict__ out) {
    __shared__ float red[4];
    int t = threadIdx.x;
    float s = 0.f;
    for (int i = t; i < 2 * NPART; i += 256)
        s += (i < NPART) ? part_c[i] : part_w[i - NPART];
    s = wave_reduce(s);
    if ((t & 63) == 0) red[t >> 6] = s;
    __syncthreads();
    if (t == 0) out[0] = (red[0] + red[1] + red[2] + red[3]) * EKJ;
}

extern "C" void kernel_launch(void* const* d_in, const int* in_sizes, int n_in,
                              void* d_out, int out_size, void* d_ws, size_t ws_size,
                              hipStream_t stream) {
    const float* pos    = (const float*)d_in[0];
    const float* na     = (const float*)d_in[1];
    const float* shifts = (const float*)d_in[2];
    const float* Wz     = (const float*)d_in[3];
    const float* W1     = (const float*)d_in[4];
    const float* b1     = (const float*)d_in[5];
    const float* W2     = (const float*)d_in[6];
    const float* Wout   = (const float*)d_in[7];
    const int*   ei     = (const int*)d_in[8];
    int N = in_sizes[0] / 3;
    int E = in_sizes[8] / 2;

    char* ws = (char*)d_ws;
    float*  Ug     = (float*)(ws + 0);                       // 640 floats
    float4* pos4   = (float4*)(ws + 4096);                   // N*16 B
    int*    spec   = (int*)(ws + 4096 + (size_t)N * 16);     // N*4 B
    float*  part_c = (float*)(ws + 4096 + (size_t)N * 20);   // NPART floats
    float*  part_w = part_c + NPART;                          // NPART floats

    int blocksP = (N + 255) / 256;
    k_prep<<<blocksP, 256, 0, stream>>>(pos, na, Wz, b1, W2, Wout, N, pos4, spec, Ug);

    k_fused<<<NPART, 256, 0, stream>>>(pos4, spec, shifts, ei, E, W1, b1, Ug,
                                       part_c, part_w);

    k_final<<<1, 256, 0, stream>>>(part_c, part_w, (float*)d_out);
}